// Round 1
// baseline (1300.161 us; speedup 1.0000x reference)
//
#include <hip/hip_runtime.h>

// LPKT forward. B=128, S=128, C=128, D=64.
// Strategy:
//  - P1/P2: parallel precompute of everything not on the sequential critical path.
//  - K3: one workgroup per batch element runs the 127-step recurrence with
//        h[128][64] in LDS and weight columns in registers.

#define NB 128
#define NS 128
#define NC 128
#define ND 64
#define POS (NB*NS)          // 16384
#define PRE_STRIDE (NS*ND)   // per-batch stride in pre arrays

__device__ __forceinline__ float sigm(float x){ return 1.f/(1.f+__expf(-x)); }

// acc += sum_j vec[j]*warr[j]  (vec: LDS broadcast, warr: register array)
#define MATVEC64(vecptr, warr, acc) do {                                  \
  _Pragma("unroll")                                                       \
  for (int jc_ = 0; jc_ < 16; ++jc_) {                                    \
    float4 v4_ = *(const float4*)((vecptr) + jc_*4);                      \
    acc = fmaf(v4_.x, warr[4*jc_+0], acc);                                \
    acc = fmaf(v4_.y, warr[4*jc_+1], acc);                                \
    acc = fmaf(v4_.z, warr[4*jc_+2], acc);                                \
    acc = fmaf(v4_.w, warr[4*jc_+3], acc);                                \
  }                                                                       \
} while(0)

// ---------------- P1: AL = [e,at,c]@W1+b1 ; pre4 = it@W4c+b4 ; pre5 = e@W5a+b5
__global__ __launch_bounds__(64) void lpkt_pre1(
    const int* __restrict__ qseq, const int* __restrict__ cseq,
    const int* __restrict__ itseq, const int* __restrict__ atseq,
    const float* __restrict__ E_q, const float* __restrict__ E_c,
    const float* __restrict__ E_it, const float* __restrict__ E_at,
    const float* __restrict__ W1, const float* __restrict__ b1,
    const float* __restrict__ W4, const float* __restrict__ b4,
    const float* __restrict__ W5, const float* __restrict__ b5,
    float* __restrict__ AL, float* __restrict__ pre4, float* __restrict__ pre5)
{
  __shared__ float sx[4][192];
  __shared__ float sit[4][64];
  const int d = threadIdx.x;
  #pragma unroll
  for (int i = 0; i < 4; ++i) {
    int p = blockIdx.x + i*4096;
    int qid  = qseq[p];
    int cid  = cseq[p];
    int itid = itseq[p];
    int atid = atseq[p];
    sx[i][d]      = E_q[qid*ND + d];
    sx[i][64+d]   = E_at[atid*ND + d];
    sx[i][128+d]  = E_c[cid*ND + d];
    sit[i][d]     = E_it[itid*ND + d];
  }
  __syncthreads();
  float al[4], p4[4], p5[4];
  const float b1d = b1[d], b4d = b4[d], b5d = b5[d];
  #pragma unroll
  for (int i = 0; i < 4; ++i) { al[i] = b1d; p4[i] = b4d; p5[i] = b5d; }
  for (int k = 0; k < 192; ++k) {
    float wv = W1[k*ND + d];
    #pragma unroll
    for (int i = 0; i < 4; ++i) al[i] = fmaf(sx[i][k], wv, al[i]);
  }
  for (int k = 0; k < 64; ++k) {
    float wv4 = W4[(128+k)*ND + d];
    float wv5 = W5[k*ND + d];
    #pragma unroll
    for (int i = 0; i < 4; ++i) {
      p4[i] = fmaf(sit[i][k], wv4, p4[i]);
      p5[i] = fmaf(sx[i][k],  wv5, p5[i]);  // e part = sx[i][0..63]
    }
  }
  #pragma unroll
  for (int i = 0; i < 4; ++i) {
    int p = blockIdx.x + i*4096;
    AL[p*ND + d]   = al[i];
    pre4[p*ND + d] = p4[i];
    pre5[p*ND + d] = p5[i];
  }
}

// ---------------- P2: pre2/pre3 = [AL(t-1)|0, it, AL(t)] @ W{2,3}[0:192] + b
__global__ __launch_bounds__(64) void lpkt_pre2(
    const int* __restrict__ itseq, const float* __restrict__ E_it,
    const float* __restrict__ AL,
    const float* __restrict__ W2, const float* __restrict__ b2,
    const float* __restrict__ W3, const float* __restrict__ b3,
    float* __restrict__ pre2, float* __restrict__ pre3)
{
  __shared__ float sx[4][192];
  const int d = threadIdx.x;
  int bs4[4];
  #pragma unroll
  for (int i = 0; i < 4; ++i) {
    int p = blockIdx.x + i*4064;          // p in [0, 128*127)
    int b = p / 127;
    int t = p - b*127;
    int bs = b*NS + t;
    bs4[i] = bs;
    sx[i][d]     = (t > 0) ? AL[(bs-1)*ND + d] : 0.f;
    sx[i][64+d]  = E_it[itseq[bs]*ND + d];
    sx[i][128+d] = AL[bs*ND + d];
  }
  __syncthreads();
  float a2[4], a3[4];
  const float b2d = b2[d], b3d = b3[d];
  #pragma unroll
  for (int i = 0; i < 4; ++i) { a2[i] = b2d; a3[i] = b3d; }
  for (int k = 0; k < 192; ++k) {
    float w2v = W2[k*ND + d];
    float w3v = W3[k*ND + d];
    #pragma unroll
    for (int i = 0; i < 4; ++i) {
      a2[i] = fmaf(sx[i][k], w2v, a2[i]);
      a3[i] = fmaf(sx[i][k], w3v, a3[i]);
    }
  }
  #pragma unroll
  for (int i = 0; i < 4; ++i) {
    pre2[bs4[i]*ND + d] = a2[i];
    pre3[bs4[i]*ND + d] = a3[i];
  }
}

// ---------------- K3: sequential recurrence, 1 block per batch element
__global__ __launch_bounds__(256) void lpkt_seq(
    const int* __restrict__ qseq, const float* __restrict__ qmat,
    const float* __restrict__ h0,
    const float* __restrict__ W2, const float* __restrict__ W3,
    const float* __restrict__ W4, const float* __restrict__ W5,
    const float* __restrict__ pre2, const float* __restrict__ pre3,
    const float* __restrict__ pre4, const float* __restrict__ pre5,
    float* __restrict__ out)
{
  __shared__ float sh_h[NC][ND];     // 32KB recurrent state
  __shared__ float sh_q[2][NC];      // q_e rows, double buffered
  __shared__ float sh_ht[ND];
  __shared__ float sh_a2[ND];
  __shared__ float sh_a3[ND];
  __shared__ float sh_LG[ND];
  __shared__ float sh_lgit[ND];
  __shared__ float sh_htp[4][ND];

  const int tid = threadIdx.x;
  const int w = tid >> 6;            // wave id 0..3
  const int d = tid & 63;            // lane / output dim
  const int b = blockIdx.x;

  // Weight columns in registers.
  // w4a[j] = W4[j][d]  (rows 0..63 of W4: the h_pre part) — used by all waves.
  // ws[j]: wave-specialized column:
  //   wave0: W2 rows 192..255 (h_tilde part)  -> a2
  //   wave1: W3 rows 192..255                  -> a3
  //   wave2: W4 rows  64..127 (LG part)        -> lgit
  //   wave3: W5 rows  64..127 (h_tilde part)   -> y
  float w4a[64], ws[64];
  const float* wsbase = (w == 0) ? (W2 + 192*ND)
                      : (w == 1) ? (W3 + 192*ND)
                      : (w == 2) ? (W4 + 64*ND)
                                 : (W5 + 64*ND);
  #pragma unroll
  for (int j = 0; j < 64; ++j) {
    w4a[j] = W4[j*ND + d];
    ws[j]  = wsbase[j*ND + d];
  }

  // init h = h0 (batch-replicated)
  for (int i = tid; i < NC*ND; i += 256) ((float*)sh_h)[i] = h0[i];
  // qe row for t=0
  {
    int q0 = qseq[b*NS + 0];
    if (tid < NC) sh_q[0][tid] = qmat[q0*NC + tid];
  }
  __syncthreads();

  // h_tilde0 = q_e[0] @ h0
  {
    float htp = 0.f;
    #pragma unroll 4
    for (int ci = 0; ci < 32; ++ci) {
      int c = w*32 + ci;
      htp = fmaf(sh_q[0][c], sh_h[c][d], htp);
    }
    sh_htp[w][d] = htp;
    __syncthreads();
    if (w == 0) sh_ht[d] = sh_htp[0][d] + sh_htp[1][d] + sh_htp[2][d] + sh_htp[3][d];
    __syncthreads();
  }

  if (tid == 0) out[b*NS + 0] = 0.f;   // pred[:,0] = 0 (d_out is poisoned before timing)

  // per-step scalars (per-lane d), prefetched
  int base0 = (b*NS + 0)*ND + d;
  float p2v = pre2[base0];
  float p3v = pre3[base0];
  float p4v = pre4[base0];
  float p5v = pre5[base0];

  for (int t = 0; t < 127; ++t) {
    const int cur = t & 1, nxt = cur ^ 1;

    // ---- Phase A: a2 (wave0), a3 (wave1), y for output position t (wave3)
    if (w == 0) {
      float acc = p2v;
      MATVEC64((const float*)sh_ht, ws, acc);
      sh_a2[d] = acc;
    } else if (w == 1) {
      float acc = p3v;
      MATVEC64((const float*)sh_ht, ws, acc);
      sh_a3[d] = acc;
    } else if (w == 3) {
      if (t > 0) {
        float acc = p5v;
        MATVEC64((const float*)sh_ht, ws, acc);
        float yv = sigm(acc);
        #pragma unroll
        for (int off = 32; off > 0; off >>= 1) yv += __shfl_down(yv, off);
        if (d == 0) out[b*NS + t] = yv * (1.f/64.f);
      }
    }
    __syncthreads();

    // ---- Phase B: LG (wave0); load q_e(t+1) (waves 2,3)
    if (w == 0) {
      float lg = tanhf(sh_a2[d]);
      float gl = sigm(sh_a3[d]);
      sh_LG[d] = gl * (lg + 1.f) * 0.5f;
    }
    if (tid >= 128) {
      int l = tid - 128;
      int qn = qseq[b*NS + t + 1];
      sh_q[nxt][l] = qmat[qn*NC + l];
    }
    __syncthreads();

    // ---- Phase C: lgit (wave2); prefetch next step's pre rows (all waves)
    if (w == 2) {
      float acc = p4v;
      MATVEC64((const float*)sh_LG, ws, acc);
      sh_lgit[d] = acc;
    }
    {
      int bs = (b*NS + t + 1)*ND + d;
      p2v = pre2[bs];
      p3v = pre3[bs];
      p4v = pre4[bs];
      p5v = pre5[bs];   // used by wave3 at t+1 (and after the loop for t=127)
    }
    __syncthreads();

    // ---- Phase D: big matmul + state update + h_tilde partial
    {
      const float LGv = sh_LG[d];
      const float lgv = sh_lgit[d];
      float htp = 0.f;
      for (int ci = 0; ci < 32; ++ci) {
        int c = w*32 + ci;
        const float* hr = &sh_h[c][0];
        float acc = 0.f;
        MATVEC64(hr, w4a, acc);                 // hW4a[c][d]
        float gf = sigm(acc + lgv);             // gamma_f
        float hv = sh_h[c][d];
        float hn = fmaf(sh_q[cur][c], LGv, gf * hv);
        sh_h[c][d] = hn;
        htp = fmaf(sh_q[nxt][c], hn, htp);
      }
      sh_htp[w][d] = htp;
    }
    __syncthreads();
    if (w == 0) sh_ht[d] = sh_htp[0][d] + sh_htp[1][d] + sh_htp[2][d] + sh_htp[3][d];
    __syncthreads();
  }

  // final output position t=127 (uses h_tilde after step 126, pre5[b][127])
  if (w == 3) {
    float acc = p5v;
    MATVEC64((const float*)sh_ht, ws, acc);
    float yv = sigm(acc);
    #pragma unroll
    for (int off = 32; off > 0; off >>= 1) yv += __shfl_down(yv, off);
    if (d == 0) out[b*NS + 127] = yv * (1.f/64.f);
  }
}

extern "C" void kernel_launch(void* const* d_in, const int* in_sizes, int n_in,
                              void* d_out, int out_size, void* d_ws, size_t ws_size,
                              hipStream_t stream)
{
  const int*   qseq  = (const int*)d_in[0];
  const int*   cseq  = (const int*)d_in[1];
  const int*   itseq = (const int*)d_in[2];
  const int*   atseq = (const int*)d_in[3];
  const float* E_q   = (const float*)d_in[4];
  const float* E_c   = (const float*)d_in[5];
  const float* E_it  = (const float*)d_in[6];
  const float* E_at  = (const float*)d_in[7];
  const float* qmat  = (const float*)d_in[8];
  const float* h0    = (const float*)d_in[9];
  const float* W1    = (const float*)d_in[10];
  const float* b1    = (const float*)d_in[11];
  const float* W2    = (const float*)d_in[12];
  const float* b2    = (const float*)d_in[13];
  const float* W3    = (const float*)d_in[14];
  const float* b3    = (const float*)d_in[15];
  const float* W4    = (const float*)d_in[16];
  const float* b4    = (const float*)d_in[17];
  const float* W5    = (const float*)d_in[18];
  const float* b5    = (const float*)d_in[19];
  float* out = (float*)d_out;

  float* wsf  = (float*)d_ws;
  float* AL   = wsf;
  float* pre2 = wsf + 1*POS*ND;
  float* pre3 = wsf + 2*POS*ND;
  float* pre4 = wsf + 3*POS*ND;
  float* pre5 = wsf + 4*POS*ND;

  lpkt_pre1<<<4096, 64, 0, stream>>>(qseq, cseq, itseq, atseq,
                                     E_q, E_c, E_it, E_at,
                                     W1, b1, W4, b4, W5, b5,
                                     AL, pre4, pre5);
  lpkt_pre2<<<4064, 64, 0, stream>>>(itseq, E_it, AL, W2, b2, W3, b3, pre2, pre3);
  lpkt_seq<<<128, 256, 0, stream>>>(qseq, qmat, h0, W2, W3, W4, W5,
                                    pre2, pre3, pre4, pre5, out);
}

// Round 2
// 452.015 us; speedup vs baseline: 2.8764x; 2.8764x over previous
//
#include <hip/hip_runtime.h>
#include <hip/hip_bf16.h>

// LPKT forward. B=128, S=128, C=128, D=64.
//  - P1/P2: parallel precompute of everything off the sequential critical path.
//  - K3: one workgroup per batch element runs the 127-step recurrence.
//        Per step: gamma_f pre-act P = h @ W4a on MFMA (bf16 in, f32 acc),
//        h state f32 in LDS (wave-local rows), small matvecs via v_readlane.

#define NB 128
#define NS 128
#define NC 128
#define ND 64
#define POS (NB*NS)

typedef __attribute__((ext_vector_type(8))) short short8;
typedef __attribute__((ext_vector_type(4))) float f32x4;

__device__ __forceinline__ float sigm(float x){ return 1.f/(1.f+__expf(-x)); }
__device__ __forceinline__ float rl(float v, int j){
  return __int_as_float(__builtin_amdgcn_readlane(__float_as_int(v), j));
}

// swizzled index into bf16 shadow of h (ushort units); XOR spreads rows across banks
#define HBF_IDX(row, cc) ((((row)<<6) + (cc)) ^ (((row)&7)<<3))

// acc = init + sum_j (lane j of src) * wcol[j], 4-way ILP to break FMA chain
__device__ __forceinline__ float rlmatvec(float src, const float* wcol, float init){
  float a0=init, a1=0.f, a2=0.f, a3=0.f;
  #pragma unroll
  for (int j=0;j<64;j+=4){
    a0 = fmaf(rl(src,j+0), wcol[j+0], a0);
    a1 = fmaf(rl(src,j+1), wcol[j+1], a1);
    a2 = fmaf(rl(src,j+2), wcol[j+2], a2);
    a3 = fmaf(rl(src,j+3), wcol[j+3], a3);
  }
  return (a0+a1)+(a2+a3);
}

// ---------------- P1: AL = [e,at,c]@W1+b1 ; pre4 = it@W4c+b4 ; pre5 = e@W5a+b5
__global__ __launch_bounds__(64) void lpkt_pre1(
    const int* __restrict__ qseq, const int* __restrict__ cseq,
    const int* __restrict__ itseq, const int* __restrict__ atseq,
    const float* __restrict__ E_q, const float* __restrict__ E_c,
    const float* __restrict__ E_it, const float* __restrict__ E_at,
    const float* __restrict__ W1, const float* __restrict__ b1,
    const float* __restrict__ W4, const float* __restrict__ b4,
    const float* __restrict__ W5, const float* __restrict__ b5,
    float* __restrict__ AL, float* __restrict__ pre4, float* __restrict__ pre5)
{
  __shared__ float sx[4][192];
  __shared__ float sit[4][64];
  const int d = threadIdx.x;
  #pragma unroll
  for (int i = 0; i < 4; ++i) {
    int p = blockIdx.x + i*4096;
    sx[i][d]      = E_q[qseq[p]*ND + d];
    sx[i][64+d]   = E_at[atseq[p]*ND + d];
    sx[i][128+d]  = E_c[cseq[p]*ND + d];
    sit[i][d]     = E_it[itseq[p]*ND + d];
  }
  __syncthreads();
  float al[4], p4[4], p5[4];
  const float b1d = b1[d], b4d = b4[d], b5d = b5[d];
  #pragma unroll
  for (int i = 0; i < 4; ++i) { al[i] = b1d; p4[i] = b4d; p5[i] = b5d; }
  for (int k = 0; k < 192; ++k) {
    float wv = W1[k*ND + d];
    #pragma unroll
    for (int i = 0; i < 4; ++i) al[i] = fmaf(sx[i][k], wv, al[i]);
  }
  for (int k = 0; k < 64; ++k) {
    float wv4 = W4[(128+k)*ND + d];
    float wv5 = W5[k*ND + d];
    #pragma unroll
    for (int i = 0; i < 4; ++i) {
      p4[i] = fmaf(sit[i][k], wv4, p4[i]);
      p5[i] = fmaf(sx[i][k],  wv5, p5[i]);
    }
  }
  #pragma unroll
  for (int i = 0; i < 4; ++i) {
    int p = blockIdx.x + i*4096;
    AL[p*ND + d]   = al[i];
    pre4[p*ND + d] = p4[i];
    pre5[p*ND + d] = p5[i];
  }
}

// ---------------- P2: pre2/pre3 = [AL(t-1)|0, it, AL(t)] @ W{2,3}[0:192] + b
__global__ __launch_bounds__(64) void lpkt_pre2(
    const int* __restrict__ itseq, const float* __restrict__ E_it,
    const float* __restrict__ AL,
    const float* __restrict__ W2, const float* __restrict__ b2,
    const float* __restrict__ W3, const float* __restrict__ b3,
    float* __restrict__ pre2, float* __restrict__ pre3)
{
  __shared__ float sx[4][192];
  const int d = threadIdx.x;
  int bs4[4];
  #pragma unroll
  for (int i = 0; i < 4; ++i) {
    int p = blockIdx.x + i*4064;
    int b = p / 127;
    int t = p - b*127;
    int bs = b*NS + t;
    bs4[i] = bs;
    sx[i][d]     = (t > 0) ? AL[(bs-1)*ND + d] : 0.f;
    sx[i][64+d]  = E_it[itseq[bs]*ND + d];
    sx[i][128+d] = AL[bs*ND + d];
  }
  __syncthreads();
  float a2[4], a3[4];
  const float b2d = b2[d], b3d = b3[d];
  #pragma unroll
  for (int i = 0; i < 4; ++i) { a2[i] = b2d; a3[i] = b3d; }
  for (int k = 0; k < 192; ++k) {
    float w2v = W2[k*ND + d];
    float w3v = W3[k*ND + d];
    #pragma unroll
    for (int i = 0; i < 4; ++i) {
      a2[i] = fmaf(sx[i][k], w2v, a2[i]);
      a3[i] = fmaf(sx[i][k], w3v, a3[i]);
    }
  }
  #pragma unroll
  for (int i = 0; i < 4; ++i) {
    pre2[bs4[i]*ND + d] = a2[i];
    pre3[bs4[i]*ND + d] = a3[i];
  }
}

// MFMA block: wave w computes P[32w..32w+31][0..63] = h_bf @ W4a_bf, stores to sh_P.
// A-frag: lane holds row=(base+li), k = 32*k0 + 8*g + [0..7] (contiguous bf16 = one b128).
// D layout: col = li, row = base + 4*g + reg.
#define MFMA_BLOCK() do {                                                    \
  short8 af[2][2];                                                           \
  _Pragma("unroll")                                                          \
  for (int mi=0;mi<2;++mi){                                                  \
    int row = 32*w + 16*mi + li;                                             \
    _Pragma("unroll")                                                        \
    for (int k0=0;k0<2;++k0){                                                \
      int idx = ((row<<6) + 32*k0 + 8*g) ^ ((row&7)<<3);                     \
      af[mi][k0] = *(const short8*)&sh_hbf[idx];                             \
    }                                                                        \
  }                                                                          \
  _Pragma("unroll")                                                          \
  for (int mi=0;mi<2;++mi){                                                  \
    _Pragma("unroll")                                                        \
    for (int n=0;n<4;++n){                                                   \
      f32x4 acc = {0.f,0.f,0.f,0.f};                                         \
      acc = __builtin_amdgcn_mfma_f32_16x16x32_bf16(af[mi][0], bfr[n][0], acc, 0,0,0); \
      acc = __builtin_amdgcn_mfma_f32_16x16x32_bf16(af[mi][1], bfr[n][1], acc, 0,0,0); \
      int rbase = 32*w + 16*mi + 4*g;                                        \
      sh_P[rbase+0][16*n+li] = acc[0];                                       \
      sh_P[rbase+1][16*n+li] = acc[1];                                       \
      sh_P[rbase+2][16*n+li] = acc[2];                                       \
      sh_P[rbase+3][16*n+li] = acc[3];                                       \
    }                                                                        \
  }                                                                          \
} while(0)

// ---------------- K3: sequential recurrence, 1 block per batch element
__global__ __launch_bounds__(256,1) void lpkt_seq(
    const int* __restrict__ qseq, const float* __restrict__ qmat,
    const float* __restrict__ h0,
    const float* __restrict__ W2, const float* __restrict__ W3,
    const float* __restrict__ W4, const float* __restrict__ W5,
    const float* __restrict__ pre2, const float* __restrict__ pre3,
    const float* __restrict__ pre4, const float* __restrict__ pre5,
    float* __restrict__ out)
{
  __shared__ float sh_h[NC][68];                       // f32 state, padded
  __shared__ float sh_P[NC][68];                       // gamma_f pre-act, padded
  __shared__ __align__(16) unsigned short sh_hbf[NC*ND]; // bf16 shadow, XOR-swizzled
  __shared__ float sh_q[2][NC];
  __shared__ float sh_htp[16][68];
  __shared__ float sh_a2[ND], sh_a3[ND], sh_LG[ND], sh_lgit[ND];

  const int tid = threadIdx.x;
  const int w = tid>>6, l = tid&63;
  const int g = l>>4, li = l&15;
  const int b = blockIdx.x;

  // wave-specialized weight column + pre-stream:
  //  w0: a2 (W2 rows 192..255, pre2)   w1: a3 (W3 rows 192..255, pre3)
  //  w2: lgit (W4 rows 64..127, pre4)  w3: y  (W5 rows 64..127, pre5)
  const float* wsbase = (w==0)? (W2+192*ND) : (w==1)? (W3+192*ND) : (w==2)? (W4+64*ND) : (W5+64*ND);
  const float* mystream = (w==0)? pre2 : (w==1)? pre3 : (w==2)? pre4 : pre5;
  float ws[64];
  #pragma unroll
  for (int j=0;j<64;++j) ws[j] = wsbase[j*ND + l];

  // W4a (rows 0..63) B-fragments, bf16, preloaded once (shared by all waves)
  short8 bfr[4][2];
  #pragma unroll
  for (int n=0;n<4;++n){
    #pragma unroll
    for (int k0=0;k0<2;++k0){
      #pragma unroll
      for (int j=0;j<8;++j){
        int k = 32*k0 + 8*g + j;
        __hip_bfloat16 hb = __float2bfloat16(W4[k*ND + 16*n + li]);
        bfr[n][k0][j] = *(short*)&hb;
      }
    }
  }

  // init h = h0 (f32 + bf16 shadow), q row t=0
  for (int i=tid;i<NC*ND;i+=256){
    int row=i>>6, cc=i&63;
    float v = h0[i];
    sh_h[row][cc] = v;
    __hip_bfloat16 hb = __float2bfloat16(v);
    sh_hbf[HBF_IDX(row,cc)] = *(unsigned short*)&hb;
  }
  if (tid < NC) sh_q[0][tid] = qmat[qseq[b*NS]*NC + tid];
  __syncthreads();

  // ht0 = q_e[0] @ h0
  {
    float part = 0.f;
    #pragma unroll 4
    for (int ci=0;ci<32;++ci){
      int cc = 32*w+ci;
      part = fmaf(sh_q[0][cc], sh_h[cc][l], part);
    }
    sh_htp[w][l] = part;
  }
  __syncthreads();
  float ht = (sh_htp[0][l] + sh_htp[1][l]) + (sh_htp[2][l] + sh_htp[3][l]);

  if (tid==0) out[b*NS] = 0.f;

  float pv = mystream[(b*NS)*ND + l];
  float nv;

  for (int t=0;t<127;++t){
    const int cur=t&1, nxt=cur^1;

    // ---- ph1: a2(w0), a3(w1), y+qe-stage(w3), MFMA(w2); prefetch next pre row
    nv = mystream[(b*NS+t+1)*ND + l];
    if (w==0){
      sh_a2[l] = rlmatvec(ht, ws, pv);
    } else if (w==1){
      sh_a3[l] = rlmatvec(ht, ws, pv);
    } else if (w==3){
      int qn = qseq[b*NS+t+1];
      float q0 = qmat[qn*NC + l];
      float q1 = qmat[qn*NC + 64 + l];
      if (t>0){
        float z = rlmatvec(ht, ws, pv);
        float yv = sigm(z);
        #pragma unroll
        for (int off=32;off>0;off>>=1) yv += __shfl_down(yv, off);
        if (l==0) out[b*NS+t] = yv*(1.f/64.f);
      }
      sh_q[nxt][l] = q0;
      sh_q[nxt][64+l] = q1;
    } else {
      MFMA_BLOCK();
    }
    __syncthreads();

    // ---- ph2: LG+lgit (w2, serial chain), MFMA (w0,w1,w3)
    if (w==2){
      float va2 = sh_a2[l], va3 = sh_a3[l];
      float LGl = sigm(va3) * (tanhf(va2)+1.f) * 0.5f;
      sh_LG[l] = LGl;
      sh_lgit[l] = rlmatvec(LGl, ws, pv);
    } else {
      MFMA_BLOCK();
    }
    __syncthreads();

    // ---- ph3: elementwise update (wave-local rows), htp partials
    {
      const float4 LG4 = *(const float4*)&sh_LG[4*li];
      const float4 gi4 = *(const float4*)&sh_lgit[4*li];
      float hx=0.f, hy=0.f, hz=0.f, hw2=0.f;
      #pragma unroll
      for (int g2=0; g2<8; ++g2){
        int cc = 32*w + 4*g2 + g;
        float4 h4 = *(const float4*)&sh_h[cc][4*li];
        float4 P4 = *(const float4*)&sh_P[cc][4*li];
        float qc = sh_q[cur][cc];
        float qn = sh_q[nxt][cc];
        float4 hn;
        hn.x = fmaf(qc, LG4.x, sigm(P4.x+gi4.x)*h4.x);
        hn.y = fmaf(qc, LG4.y, sigm(P4.y+gi4.y)*h4.y);
        hn.z = fmaf(qc, LG4.z, sigm(P4.z+gi4.z)*h4.z);
        hn.w = fmaf(qc, LG4.w, sigm(P4.w+gi4.w)*h4.w);
        *(float4*)&sh_h[cc][4*li] = hn;
        __hip_bfloat162 c01 = __float22bfloat162_rn(make_float2(hn.x, hn.y));
        __hip_bfloat162 c23 = __float22bfloat162_rn(make_float2(hn.z, hn.w));
        uint2 pk;
        pk.x = *(unsigned*)&c01;
        pk.y = *(unsigned*)&c23;
        *(uint2*)&sh_hbf[HBF_IDX(cc, 4*li)] = pk;      // b64, swizzle keeps 8B align
        hx = fmaf(qn, hn.x, hx); hy = fmaf(qn, hn.y, hy);
        hz = fmaf(qn, hn.z, hz); hw2 = fmaf(qn, hn.w, hw2);
      }
      float4 hp; hp.x=hx; hp.y=hy; hp.z=hz; hp.w=hw2;
      *(float4*)&sh_htp[4*w+g][4*li] = hp;
    }
    __syncthreads();

    // ---- ph4: reduce h_tilde (redundant per wave, register-resident)
    {
      float s = 0.f;
      #pragma unroll
      for (int i=0;i<16;++i) s += sh_htp[i][l];
      ht = s;
    }
    pv = nv;
  }

  // final output t=127
  if (w==3){
    float z = rlmatvec(ht, ws, pv);
    float yv = sigm(z);
    #pragma unroll
    for (int off=32;off>0;off>>=1) yv += __shfl_down(yv, off);
    if (l==0) out[b*NS+127] = yv*(1.f/64.f);
  }
}

extern "C" void kernel_launch(void* const* d_in, const int* in_sizes, int n_in,
                              void* d_out, int out_size, void* d_ws, size_t ws_size,
                              hipStream_t stream)
{
  const int*   qseq  = (const int*)d_in[0];
  const int*   cseq  = (const int*)d_in[1];
  const int*   itseq = (const int*)d_in[2];
  const int*   atseq = (const int*)d_in[3];
  const float* E_q   = (const float*)d_in[4];
  const float* E_c   = (const float*)d_in[5];
  const float* E_it  = (const float*)d_in[6];
  const float* E_at  = (const float*)d_in[7];
  const float* qmat  = (const float*)d_in[8];
  const float* h0    = (const float*)d_in[9];
  const float* W1    = (const float*)d_in[10];
  const float* b1    = (const float*)d_in[11];
  const float* W2    = (const float*)d_in[12];
  const float* b2    = (const float*)d_in[13];
  const float* W3    = (const float*)d_in[14];
  const float* b3    = (const float*)d_in[15];
  const float* W4    = (const float*)d_in[16];
  const float* b4    = (const float*)d_in[17];
  const float* W5    = (const float*)d_in[18];
  const float* b5    = (const float*)d_in[19];
  float* out = (float*)d_out;

  float* wsf  = (float*)d_ws;
  float* AL   = wsf;
  float* pre2 = wsf + 1*POS*ND;
  float* pre3 = wsf + 2*POS*ND;
  float* pre4 = wsf + 3*POS*ND;
  float* pre5 = wsf + 4*POS*ND;

  lpkt_pre1<<<4096, 64, 0, stream>>>(qseq, cseq, itseq, atseq,
                                     E_q, E_c, E_it, E_at,
                                     W1, b1, W4, b4, W5, b5,
                                     AL, pre4, pre5);
  lpkt_pre2<<<4064, 64, 0, stream>>>(itseq, E_it, AL, W2, b2, W3, b3, pre2, pre3);
  lpkt_seq<<<128, 256, 0, stream>>>(qseq, qmat, h0, W2, W3, W4, W5,
                                    pre2, pre3, pre4, pre5, out);
}

// Round 3
// 377.032 us; speedup vs baseline: 3.4484x; 1.1989x over previous
//
#include <hip/hip_runtime.h>
#include <hip/hip_bf16.h>

// LPKT forward. B=128, S=128, C=128, D=64.
//  - P1/P2: parallel precompute of everything off the sequential critical path.
//  - K3: one 512-thread workgroup per batch element, 127-step recurrence.
//        Per step (3 barriers): phA: ht assemble + K-split readlane dots (a2,a3,y)
//        phB: MFMA P=h@W4a (4 waves) || LG+lgit serial chain (2 waves) || y-out
//        phC: all 8 waves elementwise update (16 rows each) + shfl'd ht partials.

#define NB 128
#define NS 128
#define NC 128
#define ND 64
#define POS (NB*NS)

typedef __attribute__((ext_vector_type(8))) short short8;
typedef __attribute__((ext_vector_type(4))) float f32x4;

__device__ __forceinline__ float sigm(float x){ return 1.f/(1.f+__expf(-x)); }
__device__ __forceinline__ float tanh_fast(float x){ float e=__expf(2.f*x); return 1.f - 2.f/(e+1.f); }
__device__ __forceinline__ float rl(float v,int j){
  return __int_as_float(__builtin_amdgcn_readlane(__float_as_int(v), j));
}

#define HBF_IDX(row, cc) ((((row)<<6) + (cc)) ^ (((row)&7)<<3))

// partial dot: init + sum_{j<32} (lane koff+j of src) * wcol[j]
__device__ __forceinline__ float rlmv32(float src, const float* wcol, int koff, float init){
  float a0=init,a1=0.f,a2=0.f,a3=0.f;
  #pragma unroll
  for (int j=0;j<32;j+=4){
    a0=fmaf(rl(src,koff+j+0),wcol[j+0],a0);
    a1=fmaf(rl(src,koff+j+1),wcol[j+1],a1);
    a2=fmaf(rl(src,koff+j+2),wcol[j+2],a2);
    a3=fmaf(rl(src,koff+j+3),wcol[j+3],a3);
  }
  return (a0+a1)+(a2+a3);
}

// ---------------- P1: AL = [e,at,c]@W1+b1 ; pre4 = it@W4c+b4 ; pre5 = e@W5a+b5
__global__ __launch_bounds__(64) void lpkt_pre1(
    const int* __restrict__ qseq, const int* __restrict__ cseq,
    const int* __restrict__ itseq, const int* __restrict__ atseq,
    const float* __restrict__ E_q, const float* __restrict__ E_c,
    const float* __restrict__ E_it, const float* __restrict__ E_at,
    const float* __restrict__ W1, const float* __restrict__ b1,
    const float* __restrict__ W4, const float* __restrict__ b4,
    const float* __restrict__ W5, const float* __restrict__ b5,
    float* __restrict__ AL, float* __restrict__ pre4, float* __restrict__ pre5)
{
  __shared__ float sx[4][192];
  __shared__ float sit[4][64];
  const int d = threadIdx.x;
  #pragma unroll
  for (int i = 0; i < 4; ++i) {
    int p = blockIdx.x + i*4096;
    sx[i][d]      = E_q[qseq[p]*ND + d];
    sx[i][64+d]   = E_at[atseq[p]*ND + d];
    sx[i][128+d]  = E_c[cseq[p]*ND + d];
    sit[i][d]     = E_it[itseq[p]*ND + d];
  }
  __syncthreads();
  float al[4], p4[4], p5[4];
  const float b1d = b1[d], b4d = b4[d], b5d = b5[d];
  #pragma unroll
  for (int i = 0; i < 4; ++i) { al[i] = b1d; p4[i] = b4d; p5[i] = b5d; }
  for (int k = 0; k < 192; ++k) {
    float wv = W1[k*ND + d];
    #pragma unroll
    for (int i = 0; i < 4; ++i) al[i] = fmaf(sx[i][k], wv, al[i]);
  }
  for (int k = 0; k < 64; ++k) {
    float wv4 = W4[(128+k)*ND + d];
    float wv5 = W5[k*ND + d];
    #pragma unroll
    for (int i = 0; i < 4; ++i) {
      p4[i] = fmaf(sit[i][k], wv4, p4[i]);
      p5[i] = fmaf(sx[i][k],  wv5, p5[i]);
    }
  }
  #pragma unroll
  for (int i = 0; i < 4; ++i) {
    int p = blockIdx.x + i*4096;
    AL[p*ND + d]   = al[i];
    pre4[p*ND + d] = p4[i];
    pre5[p*ND + d] = p5[i];
  }
}

// ---------------- P2: pre2/pre3 = [AL(t-1)|0, it, AL(t)] @ W{2,3}[0:192] + b
__global__ __launch_bounds__(64) void lpkt_pre2(
    const int* __restrict__ itseq, const float* __restrict__ E_it,
    const float* __restrict__ AL,
    const float* __restrict__ W2, const float* __restrict__ b2,
    const float* __restrict__ W3, const float* __restrict__ b3,
    float* __restrict__ pre2, float* __restrict__ pre3)
{
  __shared__ float sx[4][192];
  const int d = threadIdx.x;
  int bs4[4];
  #pragma unroll
  for (int i = 0; i < 4; ++i) {
    int p = blockIdx.x + i*4064;
    int b = p / 127;
    int t = p - b*127;
    int bs = b*NS + t;
    bs4[i] = bs;
    sx[i][d]     = (t > 0) ? AL[(bs-1)*ND + d] : 0.f;
    sx[i][64+d]  = E_it[itseq[bs]*ND + d];
    sx[i][128+d] = AL[bs*ND + d];
  }
  __syncthreads();
  float a2[4], a3[4];
  const float b2d = b2[d], b3d = b3[d];
  #pragma unroll
  for (int i = 0; i < 4; ++i) { a2[i] = b2d; a3[i] = b3d; }
  for (int k = 0; k < 192; ++k) {
    float w2v = W2[k*ND + d];
    float w3v = W3[k*ND + d];
    #pragma unroll
    for (int i = 0; i < 4; ++i) {
      a2[i] = fmaf(sx[i][k], w2v, a2[i]);
      a3[i] = fmaf(sx[i][k], w3v, a3[i]);
    }
  }
  #pragma unroll
  for (int i = 0; i < 4; ++i) {
    pre2[bs4[i]*ND + d] = a2[i];
    pre3[bs4[i]*ND + d] = a3[i];
  }
}

// MFMA: wave w (0..3) computes P[32w..32w+31][:] = h_bf @ W4a_bf -> sh_P
#define MFMA_BLOCK() do {                                                    \
  short8 af[2][2];                                                           \
  _Pragma("unroll")                                                          \
  for (int mi=0;mi<2;++mi){                                                  \
    int row = 32*w + 16*mi + li;                                             \
    _Pragma("unroll")                                                        \
    for (int k0=0;k0<2;++k0){                                                \
      int idx = ((row<<6) + 32*k0 + 8*g) ^ ((row&7)<<3);                     \
      af[mi][k0] = *(const short8*)&sh_hbf[idx];                             \
    }                                                                        \
  }                                                                          \
  _Pragma("unroll")                                                          \
  for (int mi=0;mi<2;++mi){                                                  \
    _Pragma("unroll")                                                        \
    for (int n=0;n<4;++n){                                                   \
      f32x4 acc = {0.f,0.f,0.f,0.f};                                         \
      acc = __builtin_amdgcn_mfma_f32_16x16x32_bf16(af[mi][0], bfr[n][0], acc, 0,0,0); \
      acc = __builtin_amdgcn_mfma_f32_16x16x32_bf16(af[mi][1], bfr[n][1], acc, 0,0,0); \
      int rbase = 32*w + 16*mi + 4*g;                                        \
      sh_P[rbase+0][16*n+li] = acc[0];                                       \
      sh_P[rbase+1][16*n+li] = acc[1];                                       \
      sh_P[rbase+2][16*n+li] = acc[2];                                       \
      sh_P[rbase+3][16*n+li] = acc[3];                                       \
    }                                                                        \
  }                                                                          \
} while(0)

// ---------------- K3: sequential recurrence, 1 block (8 waves) per batch
__global__ __launch_bounds__(512,1) void lpkt_seq(
    const int* __restrict__ qseq, const float* __restrict__ qmat,
    const float* __restrict__ h0,
    const float* __restrict__ W2, const float* __restrict__ W3,
    const float* __restrict__ W4, const float* __restrict__ W5,
    const float* __restrict__ pre2, const float* __restrict__ pre3,
    const float* __restrict__ pre4, const float* __restrict__ pre5,
    float* __restrict__ out)
{
  __shared__ float sh_h[NC][68];
  __shared__ float sh_P[NC][68];
  __shared__ __align__(16) unsigned short sh_hbf[NC*ND];
  __shared__ float sh_q[2][NC];
  __shared__ float sh_htp[8][68];
  __shared__ float sh_pa[4][64];   // a2lo, a2hi, a3lo, a3hi
  __shared__ float sh_py[2][64];   // y lo/hi
  __shared__ float sh_lgp[2][64];  // lgit lo (incl pre4), hi
  __shared__ float sh_LG[64];

  const int tid = threadIdx.x;
  const int w = tid>>6, l = tid&63;
  const int g = l>>4, li = l&15;
  const int b = blockIdx.x;

  // ---- weights in registers
  short8 bfr[4][2];               // W4a B-frags (waves 0-3)
  if (w < 4){
    #pragma unroll
    for (int n=0;n<4;++n)
      #pragma unroll
      for (int k0=0;k0<2;++k0)
        #pragma unroll
        for (int j=0;j<8;++j){
          int k = 32*k0 + 8*g + j;
          __hip_bfloat16 hb = __float2bfloat16(W4[k*ND + 16*n + li]);
          bfr[n][k0][j] = *(short*)&hb;
        }
  }
  // wsA: K-split half-columns for the 64-dots
  //  w0: W5 rows 64..95 (y lo)   w1: W5 rows 96..127 (y hi)
  //  w4: W2 rows 192..223 (a2lo) w6: W2 rows 224..255 (a2hi)
  //  w5: W3 rows 192..223 (a3lo) w7: W3 rows 224..255 (a3hi)
  float wsA[32], wsB[32];
  {
    const float* srcA = nullptr;
    if      (w==0) srcA = W5 + 64*ND;
    else if (w==1) srcA = W5 + 96*ND;
    else if (w==4) srcA = W2 + 192*ND;
    else if (w==6) srcA = W2 + 224*ND;
    else if (w==5) srcA = W3 + 192*ND;
    else if (w==7) srcA = W3 + 224*ND;
    if (srcA){
      #pragma unroll
      for (int j=0;j<32;++j) wsA[j] = srcA[j*ND + l];
    }
    const float* srcB = (w==4)? (W4+64*ND) : (w==5)? (W4+96*ND) : nullptr;
    if (srcB){
      #pragma unroll
      for (int j=0;j<32;++j) wsB[j] = srcB[j*ND + l];
    }
  }

  // ---- init h (f32 + swizzled bf16 shadow)
  for (int k = tid; k < NC*ND/4; k += 512){
    int e = k*4;
    int row = e>>6, col = e&63;
    float4 v = *(const float4*)&h0[e];
    *(float4*)&sh_h[row][col] = v;
    __hip_bfloat162 c01 = __float22bfloat162_rn(make_float2(v.x,v.y));
    __hip_bfloat162 c23 = __float22bfloat162_rn(make_float2(v.z,v.w));
    uint2 pk; pk.x = *(unsigned*)&c01; pk.y = *(unsigned*)&c23;
    *(uint2*)&sh_hbf[HBF_IDX(row,col)] = pk;
  }

  // ---- streams + q staging
  float pv2=0.f,pv3=0.f,pv4=0.f,pv5=0.f;
  float pv2n=0.f,pv3n=0.f,pv4n=0.f,pv5n=0.f;
  {
    int base0 = (b*NS)*ND + l;
    if (w==4){ pv2=pre2[base0]; pv3=pre3[base0]; pv4=pre4[base0]; }
    else if (w==5){ pv2=pre2[base0]; pv3=pre3[base0]; }
    else if (w==6){ pv5=pre5[base0]; }
  }
  float qr0=0.f, qr1=0.f;
  if (w==2){
    int q0 = qseq[b*NS];
    sh_q[0][l]    = qmat[q0*NC + l];
    sh_q[0][64+l] = qmat[q0*NC + 64 + l];
    int q1 = qseq[b*NS + 1];
    qr0 = qmat[q1*NC + l];
    qr1 = qmat[q1*NC + 64 + l];
  }
  if (w==3 && l==0) out[b*NS] = 0.f;
  __syncthreads();

  // ---- htp0: partials of q_e[0] @ h0
  {
    float hp0=0.f,hp1=0.f,hp2=0.f,hp3=0.f;
    #pragma unroll
    for (int i=0;i<4;++i){
      int cc = 16*w + 4*i + g;
      float4 h4 = *(const float4*)&sh_h[cc][4*li];
      float qc = sh_q[0][cc];
      hp0=fmaf(qc,h4.x,hp0); hp1=fmaf(qc,h4.y,hp1);
      hp2=fmaf(qc,h4.z,hp2); hp3=fmaf(qc,h4.w,hp3);
    }
    hp0 += __shfl_xor(hp0,16); hp0 += __shfl_xor(hp0,32);
    hp1 += __shfl_xor(hp1,16); hp1 += __shfl_xor(hp1,32);
    hp2 += __shfl_xor(hp2,16); hp2 += __shfl_xor(hp2,32);
    hp3 += __shfl_xor(hp3,16); hp3 += __shfl_xor(hp3,32);
    if (g==0){
      float4 hv; hv.x=hp0; hv.y=hp1; hv.z=hp2; hv.w=hp3;
      *(float4*)&sh_htp[w][4*li] = hv;
    }
  }
  __syncthreads();

  for (int t=0; t<127; ++t){
    const int cur=t&1, nxt=cur^1;

    // ---- phA: ht assemble + K-split dots; q stage
    {
      float ht = 0.f;
      if (w!=2 && w!=3){
        #pragma unroll
        for (int i=0;i<8;++i) ht += sh_htp[i][l];
      }
      if      (w==0) sh_py[0][l] = rlmv32(ht, wsA, 0,  0.f);
      else if (w==1) sh_py[1][l] = rlmv32(ht, wsA, 32, 0.f);
      else if (w==4) sh_pa[0][l] = rlmv32(ht, wsA, 0,  0.f);
      else if (w==6) sh_pa[1][l] = rlmv32(ht, wsA, 32, 0.f);
      else if (w==5) sh_pa[2][l] = rlmv32(ht, wsA, 0,  0.f);
      else if (w==7) sh_pa[3][l] = rlmv32(ht, wsA, 32, 0.f);
      else if (w==2){
        sh_q[nxt][l]    = qr0;
        sh_q[nxt][64+l] = qr1;
      }
    }
    __syncthreads();

    // ---- phB: MFMA (w0-3) || LG+lgit (w4,w5) || y out (w6)
    if (w < 4){
      MFMA_BLOCK();
    } else if (w==4 || w==5){
      float a2v = sh_pa[0][l] + sh_pa[1][l] + pv2;
      float a3v = sh_pa[2][l] + sh_pa[3][l] + pv3;
      float LGl = sigm(a3v) * (tanh_fast(a2v) + 1.f) * 0.5f;
      if (w==4){
        sh_LG[l] = LGl;
        sh_lgp[0][l] = rlmv32(LGl, wsB, 0, pv4);
      } else {
        sh_lgp[1][l] = rlmv32(LGl, wsB, 32, 0.f);
      }
    } else if (w==6){
      if (t > 0){
        float yv = sigm(sh_py[0][l] + sh_py[1][l] + pv5);
        #pragma unroll
        for (int off=32;off>0;off>>=1) yv += __shfl_down(yv,off);
        if (l==0) out[b*NS+t] = yv*(1.f/64.f);
      }
    }
    __syncthreads();

    // ---- phC: global prefetch + update (all waves, 16 rows each) + ht partials
    {
      int nb = (b*NS + t + 1)*ND + l;
      if (w==4){ pv2n=pre2[nb]; pv3n=pre3[nb]; pv4n=pre4[nb]; }
      else if (w==5){ pv2n=pre2[nb]; pv3n=pre3[nb]; }
      else if (w==6){ pv5n=pre5[nb]; }
      else if (w==2 && t < 126){
        int qn = qseq[b*NS + t + 2];
        qr0 = qmat[qn*NC + l];
        qr1 = qmat[qn*NC + 64 + l];
      }

      const float4 LG4 = *(const float4*)&sh_LG[4*li];
      float4 g0v = *(const float4*)&sh_lgp[0][4*li];
      float4 g1v = *(const float4*)&sh_lgp[1][4*li];
      float gx = g0v.x+g1v.x, gy = g0v.y+g1v.y, gz = g0v.z+g1v.z, gw = g0v.w+g1v.w;

      float hp0=0.f,hp1=0.f,hp2=0.f,hp3=0.f;
      #pragma unroll
      for (int i=0;i<4;++i){
        int cc = 16*w + 4*i + g;
        float4 h4 = *(const float4*)&sh_h[cc][4*li];
        float4 P4 = *(const float4*)&sh_P[cc][4*li];
        float qc = sh_q[cur][cc];
        float qn = sh_q[nxt][cc];
        float4 hn;
        hn.x = fmaf(qc, LG4.x, sigm(P4.x+gx)*h4.x);
        hn.y = fmaf(qc, LG4.y, sigm(P4.y+gy)*h4.y);
        hn.z = fmaf(qc, LG4.z, sigm(P4.z+gz)*h4.z);
        hn.w = fmaf(qc, LG4.w, sigm(P4.w+gw)*h4.w);
        *(float4*)&sh_h[cc][4*li] = hn;
        __hip_bfloat162 c01 = __float22bfloat162_rn(make_float2(hn.x,hn.y));
        __hip_bfloat162 c23 = __float22bfloat162_rn(make_float2(hn.z,hn.w));
        uint2 pk; pk.x = *(unsigned*)&c01; pk.y = *(unsigned*)&c23;
        *(uint2*)&sh_hbf[HBF_IDX(cc,4*li)] = pk;
        hp0=fmaf(qn,hn.x,hp0); hp1=fmaf(qn,hn.y,hp1);
        hp2=fmaf(qn,hn.z,hp2); hp3=fmaf(qn,hn.w,hp3);
      }
      hp0 += __shfl_xor(hp0,16); hp0 += __shfl_xor(hp0,32);
      hp1 += __shfl_xor(hp1,16); hp1 += __shfl_xor(hp1,32);
      hp2 += __shfl_xor(hp2,16); hp2 += __shfl_xor(hp2,32);
      hp3 += __shfl_xor(hp3,16); hp3 += __shfl_xor(hp3,32);
      if (g==0){
        float4 hv; hv.x=hp0; hv.y=hp1; hv.z=hp2; hv.w=hp3;
        *(float4*)&sh_htp[w][4*li] = hv;
      }

      if (w==4){ pv2=pv2n; pv3=pv3n; pv4=pv4n; }
      else if (w==5){ pv2=pv2n; pv3=pv3n; }
      else if (w==6){ pv5=pv5n; }
    }
    __syncthreads();
  }

  // ---- final output t=127
  {
    float ht = 0.f;
    if (w < 2){
      #pragma unroll
      for (int i=0;i<8;++i) ht += sh_htp[i][l];
    }
    if      (w==0) sh_py[0][l] = rlmv32(ht, wsA, 0,  0.f);
    else if (w==1) sh_py[1][l] = rlmv32(ht, wsA, 32, 0.f);
  }
  __syncthreads();
  if (w==6){
    float yv = sigm(sh_py[0][l] + sh_py[1][l] + pv5);
    #pragma unroll
    for (int off=32;off>0;off>>=1) yv += __shfl_down(yv,off);
    if (l==0) out[b*NS+127] = yv*(1.f/64.f);
  }
}

extern "C" void kernel_launch(void* const* d_in, const int* in_sizes, int n_in,
                              void* d_out, int out_size, void* d_ws, size_t ws_size,
                              hipStream_t stream)
{
  const int*   qseq  = (const int*)d_in[0];
  const int*   cseq  = (const int*)d_in[1];
  const int*   itseq = (const int*)d_in[2];
  const int*   atseq = (const int*)d_in[3];
  const float* E_q   = (const float*)d_in[4];
  const float* E_c   = (const float*)d_in[5];
  const float* E_it  = (const float*)d_in[6];
  const float* E_at  = (const float*)d_in[7];
  const float* qmat  = (const float*)d_in[8];
  const float* h0    = (const float*)d_in[9];
  const float* W1    = (const float*)d_in[10];
  const float* b1    = (const float*)d_in[11];
  const float* W2    = (const float*)d_in[12];
  const float* b2    = (const float*)d_in[13];
  const float* W3    = (const float*)d_in[14];
  const float* b3    = (const float*)d_in[15];
  const float* W4    = (const float*)d_in[16];
  const float* b4    = (const float*)d_in[17];
  const float* W5    = (const float*)d_in[18];
  const float* b5    = (const float*)d_in[19];
  float* out = (float*)d_out;

  float* wsf  = (float*)d_ws;
  float* AL   = wsf;
  float* pre2 = wsf + 1*POS*ND;
  float* pre3 = wsf + 2*POS*ND;
  float* pre4 = wsf + 3*POS*ND;
  float* pre5 = wsf + 4*POS*ND;

  lpkt_pre1<<<4096, 64, 0, stream>>>(qseq, cseq, itseq, atseq,
                                     E_q, E_c, E_it, E_at,
                                     W1, b1, W4, b4, W5, b5,
                                     AL, pre4, pre5);
  lpkt_pre2<<<4064, 64, 0, stream>>>(itseq, E_it, AL, W2, b2, W3, b3, pre2, pre3);
  lpkt_seq<<<128, 512, 0, stream>>>(qseq, qmat, h0, W2, W3, W4, W5,
                                    pre2, pre3, pre4, pre5, out);
}

// Round 4
// 362.815 us; speedup vs baseline: 3.5835x; 1.0392x over previous
//
#include <hip/hip_runtime.h>
#include <hip/hip_bf16.h>

// LPKT forward. B=128, S=128, C=128, D=64.
//  - P1/P2: parallel precompute off the sequential critical path.
//  - K3: one 512-thread workgroup per batch element, 127-step recurrence.
//    h state entirely in REGISTERS (8 waves x 32c x 32d), bf16 shadow in LDS
//    for the swapped MFMA (P^T = W4a^T @ h^T). Zero per-step global traffic:
//    q rows as bitmasks (LDS), pre-streams staged via 32-slot LDS ring
//    (refill every 16 steps), outputs buffered in LDS.

#define NB 128
#define NS 128
#define NC 128
#define ND 64
#define POS (NB*NS)

typedef __attribute__((ext_vector_type(8))) short short8;
typedef __attribute__((ext_vector_type(4))) float f32x4;

__device__ __forceinline__ float sigm(float x){ return 1.f/(1.f+__expf(-x)); }
__device__ __forceinline__ float tanh_fast(float x){ float e=__expf(2.f*x); return 1.f - 2.f/(e+1.f); }
__device__ __forceinline__ float rl(float v,int j){
  return __int_as_float(__builtin_amdgcn_readlane(__float_as_int(v), j));
}

// ushort-index into swizzled bf16 shadow: element (c, d) of h
#define HBF(c, d) ((((c)<<6) + (d)) ^ (((c)&7)<<3))

// inclusive row-sum over 16-lane DPP rows; lane 16g+15 holds the row sum
#define DPP_ADD(v, CTRL) ((v) + __int_as_float(__builtin_amdgcn_update_dpp(0, __float_as_int(v), CTRL, 0xF, 0xF, true)))
#define DPP_ROWSUM(v) do { v = DPP_ADD(v,0x111); v = DPP_ADD(v,0x112); v = DPP_ADD(v,0x114); v = DPP_ADD(v,0x118); } while(0)

// init + sum_{j<32} (lane koff+j of src) * wcol[j]
__device__ __forceinline__ float rlmv32(float src, const float* wcol, int koff, float init){
  float a0=init,a1=0.f,a2=0.f,a3=0.f;
  #pragma unroll
  for (int j=0;j<32;j+=4){
    a0=fmaf(rl(src,koff+j+0),wcol[j+0],a0);
    a1=fmaf(rl(src,koff+j+1),wcol[j+1],a1);
    a2=fmaf(rl(src,koff+j+2),wcol[j+2],a2);
    a3=fmaf(rl(src,koff+j+3),wcol[j+3],a3);
  }
  return (a0+a1)+(a2+a3);
}

// ---------------- P1: AL = [e,at,c]@W1+b1 ; pre4 = it@W4c+b4 ; pre5 = e@W5a+b5
__global__ __launch_bounds__(64) void lpkt_pre1(
    const int* __restrict__ qseq, const int* __restrict__ cseq,
    const int* __restrict__ itseq, const int* __restrict__ atseq,
    const float* __restrict__ E_q, const float* __restrict__ E_c,
    const float* __restrict__ E_it, const float* __restrict__ E_at,
    const float* __restrict__ W1, const float* __restrict__ b1,
    const float* __restrict__ W4, const float* __restrict__ b4,
    const float* __restrict__ W5, const float* __restrict__ b5,
    float* __restrict__ AL, float* __restrict__ pre4, float* __restrict__ pre5)
{
  __shared__ float sx[4][192];
  __shared__ float sit[4][64];
  const int d = threadIdx.x;
  #pragma unroll
  for (int i = 0; i < 4; ++i) {
    int p = blockIdx.x + i*4096;
    sx[i][d]      = E_q[qseq[p]*ND + d];
    sx[i][64+d]   = E_at[atseq[p]*ND + d];
    sx[i][128+d]  = E_c[cseq[p]*ND + d];
    sit[i][d]     = E_it[itseq[p]*ND + d];
  }
  __syncthreads();
  float al[4], p4[4], p5[4];
  const float b1d = b1[d], b4d = b4[d], b5d = b5[d];
  #pragma unroll
  for (int i = 0; i < 4; ++i) { al[i] = b1d; p4[i] = b4d; p5[i] = b5d; }
  for (int k = 0; k < 192; ++k) {
    float wv = W1[k*ND + d];
    #pragma unroll
    for (int i = 0; i < 4; ++i) al[i] = fmaf(sx[i][k], wv, al[i]);
  }
  for (int k = 0; k < 64; ++k) {
    float wv4 = W4[(128+k)*ND + d];
    float wv5 = W5[k*ND + d];
    #pragma unroll
    for (int i = 0; i < 4; ++i) {
      p4[i] = fmaf(sit[i][k], wv4, p4[i]);
      p5[i] = fmaf(sx[i][k],  wv5, p5[i]);
    }
  }
  #pragma unroll
  for (int i = 0; i < 4; ++i) {
    int p = blockIdx.x + i*4096;
    AL[p*ND + d]   = al[i];
    pre4[p*ND + d] = p4[i];
    pre5[p*ND + d] = p5[i];
  }
}

// ---------------- P2: pre2/pre3 = [AL(t-1)|0, it, AL(t)] @ W{2,3}[0:192] + b
__global__ __launch_bounds__(64) void lpkt_pre2(
    const int* __restrict__ itseq, const float* __restrict__ E_it,
    const float* __restrict__ AL,
    const float* __restrict__ W2, const float* __restrict__ b2,
    const float* __restrict__ W3, const float* __restrict__ b3,
    float* __restrict__ pre2, float* __restrict__ pre3)
{
  __shared__ float sx[4][192];
  const int d = threadIdx.x;
  int bs4[4];
  #pragma unroll
  for (int i = 0; i < 4; ++i) {
    int p = blockIdx.x + i*4064;
    int b = p / 127;
    int t = p - b*127;
    int bs = b*NS + t;
    bs4[i] = bs;
    sx[i][d]     = (t > 0) ? AL[(bs-1)*ND + d] : 0.f;
    sx[i][64+d]  = E_it[itseq[bs]*ND + d];
    sx[i][128+d] = AL[bs*ND + d];
  }
  __syncthreads();
  float a2[4], a3[4];
  const float b2d = b2[d], b3d = b3[d];
  #pragma unroll
  for (int i = 0; i < 4; ++i) { a2[i] = b2d; a3[i] = b3d; }
  for (int k = 0; k < 192; ++k) {
    float w2v = W2[k*ND + d];
    float w3v = W3[k*ND + d];
    #pragma unroll
    for (int i = 0; i < 4; ++i) {
      a2[i] = fmaf(sx[i][k], w2v, a2[i]);
      a3[i] = fmaf(sx[i][k], w3v, a3[i]);
    }
  }
  #pragma unroll
  for (int i = 0; i < 4; ++i) {
    pre2[bs4[i]*ND + d] = a2[i];
    pre3[bs4[i]*ND + d] = a3[i];
  }
}

// ---------------- K3: sequential recurrence
__global__ __launch_bounds__(512,1) void lpkt_seq(
    const int* __restrict__ qseq, const float* __restrict__ qmat,
    const float* __restrict__ h0,
    const float* __restrict__ W2, const float* __restrict__ W3,
    const float* __restrict__ W4, const float* __restrict__ W5,
    const float* __restrict__ pre2, const float* __restrict__ pre3,
    const float* __restrict__ pre4, const float* __restrict__ pre5,
    float* __restrict__ out)
{
  __shared__ __align__(16) unsigned short sh_hbf[NC*ND];  // 16KB bf16 shadow (swizzled)
  __shared__ float sh_pre[4][32][64];                     // 32KB pre-stream ring
  __shared__ __align__(16) unsigned sh_qb[NS][4];         // 2KB q bitmasks
  __shared__ float sh_htp[4][64];                         // h_tilde partials
  __shared__ float sh_pa[4][64];                          // a2lo,a2hi,a3lo,a3hi
  __shared__ float sh_py[64];                             // y-lo
  __shared__ float sh_LG[64];
  __shared__ float sh_lgp[2][64];
  __shared__ float sh_out[NS];

  const int tid = threadIdx.x;
  const int w = tid>>6, l = tid&63;
  const int g = l>>4, li = l&15;
  const int b = blockIdx.x;
  const int Wq = w & 3;            // c-block: c in [32*Wq, 32*Wq+32)
  const int mm = (w>>2)*2;         // m-tile base: d in [32*(w>>2), +32)

  // ---- static weights in registers
  // A-frags for P^T = W4a^T @ h^T: aW[mloc][k0] covers m-tile mm+mloc, k-block k0
  short8 aW[2][2];
  #pragma unroll
  for (int mloc=0;mloc<2;++mloc){
    #pragma unroll
    for (int k0=0;k0<2;++k0){
      short8 v;
      #pragma unroll
      for (int j=0;j<8;++j){
        __hip_bfloat16 hb = __float2bfloat16(W4[(32*k0+8*g+j)*ND + 16*(mm+mloc)+li]);
        v[j] = *(short*)&hb;
      }
      aW[mloc][k0] = v;
    }
  }
  // wsA: 32-row weight column slices for the serial dots
  //  w0: a2-lo (W2 r192..223)  w1: a2-hi (W2 r224..255)
  //  w2: a3-lo (W3 r192..223)  w6: a3-hi (W3 r224..255)
  //  w3: y-lo  (W5 r64..95)    w7: y-hi  (W5 r96..127)
  float wsA[32];
  {
    const float* srcA = nullptr;
    if      (w==0) srcA = W2 + 192*ND;
    else if (w==1) srcA = W2 + 224*ND;
    else if (w==2) srcA = W3 + 192*ND;
    else if (w==6) srcA = W3 + 224*ND;
    else if (w==3) srcA = W5 + 64*ND;
    else if (w==7) srcA = W5 + 96*ND;
    if (srcA){
      #pragma unroll
      for (int j=0;j<32;++j) wsA[j] = srcA[j*ND + l];
    }
  }
  // wsB: lgit halves (W4 rows 64..127)
  float wsB[32];
  if (w==4 || w==5){
    const float* srcB = W4 + (w==4 ? 64 : 96)*ND;
    #pragma unroll
    for (int j=0;j<32;++j) wsB[j] = srcB[j*ND + l];
  }

  // ---- init h in registers + bf16 shadow
  float hreg[2][2][4];
  #pragma unroll
  for (int mloc=0;mloc<2;++mloc){
    #pragma unroll
    for (int t2=0;t2<2;++t2){
      int c  = 32*Wq + 16*t2 + li;
      int d0 = 16*(mm+mloc) + 4*g;
      float4 v = *(const float4*)&h0[c*ND + d0];
      hreg[mloc][t2][0]=v.x; hreg[mloc][t2][1]=v.y;
      hreg[mloc][t2][2]=v.z; hreg[mloc][t2][3]=v.w;
      __hip_bfloat162 c01 = __float22bfloat162_rn(make_float2(v.x,v.y));
      __hip_bfloat162 c23 = __float22bfloat162_rn(make_float2(v.z,v.w));
      uint2 pk; pk.x = *(unsigned*)&c01; pk.y = *(unsigned*)&c23;
      *(uint2*)&sh_hbf[HBF(c,d0)] = pk;
    }
  }

  // ---- q bitmasks: one wave per position, 16 positions/wave
  for (int s = w; s < NS; s += 8){
    int row = qseq[b*NS + s];
    float v0 = qmat[row*NC + l];
    float v1 = qmat[row*NC + 64 + l];
    unsigned long long m0 = __ballot(v0 != 0.f);
    unsigned long long m1 = __ballot(v1 != 0.f);
    if (l == 0){
      uint4 u; u.x=(unsigned)m0; u.y=(unsigned)(m0>>32);
      u.z=(unsigned)m1; u.w=(unsigned)(m1>>32);
      *(uint4*)&sh_qb[s][0] = u;
    }
  }

  // ---- pre-stream ring init: slots 0..31 (steps 0..31), 4 float4/thread
  #pragma unroll
  for (int k=0;k<4;++k){
    int f4id = tid*4 + k;            // 0..2047
    int r = f4id >> 4;               // 0..127
    int col = (f4id & 15)*4;
    int s = r >> 5, off = r & 31;
    const float* ps = (s==0)?pre2:(s==1)?pre3:(s==2)?pre4:pre5;
    float4 v = *(const float4*)&ps[(b*NS + off)*ND + col];
    *(float4*)&sh_pre[s][off][col] = v;
  }
  if (tid==0) sh_out[0] = 0.f;
  __syncthreads();

  // ---- bootstrap h_tilde partials: q0 . h_init
  {
    unsigned qwn = sh_qb[0][Wq];
    float part[2][4];
    #pragma unroll
    for (int mloc=0;mloc<2;++mloc)
      #pragma unroll
      for (int r=0;r<4;++r) part[mloc][r] = 0.f;
    #pragma unroll
    for (int t2=0;t2<2;++t2){
      float qnf = (float)((qwn>>(16*t2+li))&1u);
      #pragma unroll
      for (int mloc=0;mloc<2;++mloc)
        #pragma unroll
        for (int r=0;r<4;++r)
          part[mloc][r] = fmaf(qnf, hreg[mloc][t2][r], part[mloc][r]);
    }
    #pragma unroll
    for (int mloc=0;mloc<2;++mloc)
      #pragma unroll
      for (int r=0;r<4;++r){ float v=part[mloc][r]; DPP_ROWSUM(v); part[mloc][r]=v; }
    if (li==15){
      #pragma unroll
      for (int mloc=0;mloc<2;++mloc){
        float4 pv; pv.x=part[mloc][0]; pv.y=part[mloc][1]; pv.z=part[mloc][2]; pv.w=part[mloc][3];
        *(float4*)&sh_htp[Wq][16*(mm+mloc)+4*g] = pv;
      }
    }
  }
  __syncthreads();

  for (int t=0; t<127; ++t){
    const int slot = t & 31;

    // ---- phA: serial dots (K-split halves) using ht assembled from partials
    if (w==0 || w==1 || w==2 || w==6 || w==3){
      float ht = (sh_htp[0][l]+sh_htp[1][l])+(sh_htp[2][l]+sh_htp[3][l]);
      if      (w==0) sh_pa[0][l] = rlmv32(ht, wsA, 0,  0.f);
      else if (w==1) sh_pa[1][l] = rlmv32(ht, wsA, 32, 0.f);
      else if (w==2) sh_pa[2][l] = rlmv32(ht, wsA, 0,  0.f);
      else if (w==6) sh_pa[3][l] = rlmv32(ht, wsA, 32, 0.f);
      else           sh_py[l]    = rlmv32(ht, wsA, 0,  0.f);   // y-lo
    }
    __syncthreads();

    // ---- phB: MFMA (all waves) || LG chain (w4,w5) || y finish (w7)
    f32x4 acc[2][2];
    #pragma unroll
    for (int mloc=0;mloc<2;++mloc)
      #pragma unroll
      for (int t2=0;t2<2;++t2)
        acc[mloc][t2] = (f32x4){0.f,0.f,0.f,0.f};
    #pragma unroll
    for (int t2=0;t2<2;++t2){
      #pragma unroll
      for (int k0=0;k0<2;++k0){
        short8 bf = *(const short8*)&sh_hbf[HBF(32*Wq+16*t2+li, 32*k0+8*g)];
        acc[0][t2] = __builtin_amdgcn_mfma_f32_16x16x32_bf16(aW[0][k0], bf, acc[0][t2], 0,0,0);
        acc[1][t2] = __builtin_amdgcn_mfma_f32_16x16x32_bf16(aW[1][k0], bf, acc[1][t2], 0,0,0);
      }
    }
    if (w==4 || w==5){
      float pv2 = sh_pre[0][slot][l], pv3 = sh_pre[1][slot][l];
      float a2v = sh_pa[0][l] + sh_pa[1][l] + pv2;
      float a3v = sh_pa[2][l] + sh_pa[3][l] + pv3;
      float LGl = sigm(a3v)*(tanh_fast(a2v)+1.f)*0.5f;
      if (w==4){
        sh_LG[l] = LGl;
        sh_lgp[0][l] = rlmv32(LGl, wsB, 0, sh_pre[2][slot][l]);
      } else {
        sh_lgp[1][l] = rlmv32(LGl, wsB, 32, 0.f);
      }
    } else if (w==7){
      if (t > 0){
        float ht = (sh_htp[0][l]+sh_htp[1][l])+(sh_htp[2][l]+sh_htp[3][l]);
        float z = rlmv32(ht, wsA, 32, sh_pre[3][slot][l] + sh_py[l]);
        float yv = sigm(z);
        DPP_ROWSUM(yv);
        float s = (rl(yv,15)+rl(yv,31))+(rl(yv,47)+rl(yv,63));
        if (l==0) sh_out[t] = s*(1.f/64.f);
      }
    }
    __syncthreads();

    // ---- phC: elementwise update in regs + bf16 shadow + DPP ht partials
    {
      unsigned qwc = sh_qb[t][Wq];
      unsigned qwn = sh_qb[t+1][Wq];
      float4 LG4[2], GI[2];
      #pragma unroll
      for (int mloc=0;mloc<2;++mloc){
        int d0 = 16*(mm+mloc)+4*g;
        LG4[mloc] = *(const float4*)&sh_LG[d0];
        float4 g0 = *(const float4*)&sh_lgp[0][d0];
        float4 g1 = *(const float4*)&sh_lgp[1][d0];
        float4 gi; gi.x=g0.x+g1.x; gi.y=g0.y+g1.y; gi.z=g0.z+g1.z; gi.w=g0.w+g1.w;
        GI[mloc] = gi;
      }
      float part[2][4];
      #pragma unroll
      for (int mloc=0;mloc<2;++mloc)
        #pragma unroll
        for (int r=0;r<4;++r) part[mloc][r] = 0.f;
      #pragma unroll
      for (int t2=0;t2<2;++t2){
        int c = 32*Wq + 16*t2 + li;
        float qcf = (float)((qwc>>(16*t2+li))&1u);
        float qnf = (float)((qwn>>(16*t2+li))&1u);
        #pragma unroll
        for (int mloc=0;mloc<2;++mloc){
          float hn0 = fmaf(qcf, LG4[mloc].x, sigm(acc[mloc][t2][0]+GI[mloc].x)*hreg[mloc][t2][0]);
          float hn1 = fmaf(qcf, LG4[mloc].y, sigm(acc[mloc][t2][1]+GI[mloc].y)*hreg[mloc][t2][1]);
          float hn2 = fmaf(qcf, LG4[mloc].z, sigm(acc[mloc][t2][2]+GI[mloc].z)*hreg[mloc][t2][2]);
          float hn3 = fmaf(qcf, LG4[mloc].w, sigm(acc[mloc][t2][3]+GI[mloc].w)*hreg[mloc][t2][3]);
          hreg[mloc][t2][0]=hn0; hreg[mloc][t2][1]=hn1;
          hreg[mloc][t2][2]=hn2; hreg[mloc][t2][3]=hn3;
          part[mloc][0] = fmaf(qnf, hn0, part[mloc][0]);
          part[mloc][1] = fmaf(qnf, hn1, part[mloc][1]);
          part[mloc][2] = fmaf(qnf, hn2, part[mloc][2]);
          part[mloc][3] = fmaf(qnf, hn3, part[mloc][3]);
          __hip_bfloat162 c01 = __float22bfloat162_rn(make_float2(hn0,hn1));
          __hip_bfloat162 c23 = __float22bfloat162_rn(make_float2(hn2,hn3));
          uint2 pk; pk.x=*(unsigned*)&c01; pk.y=*(unsigned*)&c23;
          *(uint2*)&sh_hbf[HBF(c, 16*(mm+mloc)+4*g)] = pk;
        }
      }
      #pragma unroll
      for (int mloc=0;mloc<2;++mloc)
        #pragma unroll
        for (int r=0;r<4;++r){ float v=part[mloc][r]; DPP_ROWSUM(v); part[mloc][r]=v; }
      if (li==15){
        #pragma unroll
        for (int mloc=0;mloc<2;++mloc){
          float4 pv; pv.x=part[mloc][0]; pv.y=part[mloc][1]; pv.z=part[mloc][2]; pv.w=part[mloc][3];
          *(float4*)&sh_htp[Wq][16*(mm+mloc)+4*g] = pv;
        }
      }
      // ring refill: every 16 steps, load steps t+17..t+32 (2 float4/thread)
      if ((t & 15)==15 && t < 110){
        int t0 = t + 17;
        #pragma unroll
        for (int k=0;k<2;++k){
          int f4id = tid*2 + k;        // 0..1023
          int r = f4id >> 4;           // 0..63
          int col = (f4id & 15)*4;
          int s = r >> 4, off = r & 15;
          const float* ps = (s==0)?pre2:(s==1)?pre3:(s==2)?pre4:pre5;
          float4 v = *(const float4*)&ps[(b*NS + t0 + off)*ND + col];
          *(float4*)&sh_pre[s][(t0+off)&31][col] = v;
        }
      }
    }
    __syncthreads();
  }

  // ---- final output position 127
  if (w==3){
    float ht = (sh_htp[0][l]+sh_htp[1][l])+(sh_htp[2][l]+sh_htp[3][l]);
    sh_py[l] = rlmv32(ht, wsA, 0, 0.f);
  }
  __syncthreads();
  if (w==7){
    float ht = (sh_htp[0][l]+sh_htp[1][l])+(sh_htp[2][l]+sh_htp[3][l]);
    float z = rlmv32(ht, wsA, 32, sh_pre[3][31][l] + sh_py[l]);
    float yv = sigm(z);
    DPP_ROWSUM(yv);
    float s = (rl(yv,15)+rl(yv,31))+(rl(yv,47)+rl(yv,63));
    if (l==0) sh_out[127] = s*(1.f/64.f);
  }
  __syncthreads();
  if (tid < NS) out[b*NS + tid] = sh_out[tid];
}

extern "C" void kernel_launch(void* const* d_in, const int* in_sizes, int n_in,
                              void* d_out, int out_size, void* d_ws, size_t ws_size,
                              hipStream_t stream)
{
  const int*   qseq  = (const int*)d_in[0];
  const int*   cseq  = (const int*)d_in[1];
  const int*   itseq = (const int*)d_in[2];
  const int*   atseq = (const int*)d_in[3];
  const float* E_q   = (const float*)d_in[4];
  const float* E_c   = (const float*)d_in[5];
  const float* E_it  = (const float*)d_in[6];
  const float* E_at  = (const float*)d_in[7];
  const float* qmat  = (const float*)d_in[8];
  const float* h0    = (const float*)d_in[9];
  const float* W1    = (const float*)d_in[10];
  const float* b1    = (const float*)d_in[11];
  const float* W2    = (const float*)d_in[12];
  const float* b2    = (const float*)d_in[13];
  const float* W3    = (const float*)d_in[14];
  const float* b3    = (const float*)d_in[15];
  const float* W4    = (const float*)d_in[16];
  const float* b4    = (const float*)d_in[17];
  const float* W5    = (const float*)d_in[18];
  const float* b5    = (const float*)d_in[19];
  float* out = (float*)d_out;

  float* wsf  = (float*)d_ws;
  float* AL   = wsf;
  float* pre2 = wsf + 1*POS*ND;
  float* pre3 = wsf + 2*POS*ND;
  float* pre4 = wsf + 3*POS*ND;
  float* pre5 = wsf + 4*POS*ND;

  lpkt_pre1<<<4096, 64, 0, stream>>>(qseq, cseq, itseq, atseq,
                                     E_q, E_c, E_it, E_at,
                                     W1, b1, W4, b4, W5, b5,
                                     AL, pre4, pre5);
  lpkt_pre2<<<4064, 64, 0, stream>>>(itseq, E_it, AL, W2, b2, W3, b3, pre2, pre3);
  lpkt_seq<<<128, 512, 0, stream>>>(qseq, qmat, h0, W2, W3, W4, W5,
                                    pre2, pre3, pre4, pre5, out);
}